// Round 14
// baseline (61.329 us; speedup 1.0000x reference)
//
#include <hip/hip_runtime.h>
#include <hip/hip_bf16.h>
#include <cstdint>
#include <cstddef>

#define B_  2
#define Q_  256
#define KL  2048
#define D_  256
#define H_  8
#define HD_ 32
#define CH_ 256

typedef _Float16 f16;
typedef __fp16 fp16x2 __attribute__((ext_vector_type(2)));
typedef _Float16 f16x8 __attribute__((ext_vector_type(8)));
typedef unsigned short ushortv4 __attribute__((ext_vector_type(4)));
typedef unsigned int uintv4 __attribute__((ext_vector_type(4)));
typedef float f32x4 __attribute__((ext_vector_type(4)));

union UH  { fp16x2 h; unsigned int u; };
union UH8 { f16x8 h; unsigned int u[4]; };

__device__ __forceinline__ unsigned int pkrtz(float a, float b) {
  UH r; r.h = __builtin_amdgcn_cvt_pkrtz(a, b); return r.u;
}
__device__ __forceinline__ unsigned short f16bits(float a) {
  return (unsigned short)(pkrtz(a, 0.f) & 0xffffu);
}
__device__ __forceinline__ unsigned int pk_fma(unsigned int a, unsigned int b,
                                               unsigned int c) {
  unsigned int d;
  asm("v_pk_fma_f16 %0, %1, %2, %3" : "=v"(d) : "v"(a), "v"(b), "v"(c));
  return d;
}
__device__ __forceinline__ unsigned int pk_max0(unsigned int a) {
  unsigned int d;
  asm("v_pk_max_f16 %0, %1, %2" : "=v"(d) : "v"(a), "v"(0u));
  return d;
}
__device__ __forceinline__ unsigned int pk_mul(unsigned int a, unsigned int b) {
  unsigned int d;
  asm("v_pk_mul_f16 %0, %1, %2" : "=v"(d) : "v"(a), "v"(b));
  return d;
}

// ---------- prep: convert fp32 row-major sources to f16 MFMA-fragment layout
// frag array: ((f16x8*)dst)[(tile*8 + s)*64 + lane] =
//   src[tile*16 + (lane&15)][s*32 + (lane>>4)*8 .. +8]
// tiles: [0,32) ent | [32,288) img | [288,304) Wq | [304,336) Wkv | [336,352) Wo
__global__ __launch_bounds__(512) void prep(
    const float* __restrict__ ent, const float* __restrict__ img,
    const float* __restrict__ Wq, const float* __restrict__ Wkv,
    const float* __restrict__ Wo,
    unsigned short* __restrict__ entS, unsigned short* __restrict__ imgS,
    unsigned short* __restrict__ WqS, unsigned short* __restrict__ WkvS,
    unsigned short* __restrict__ WoS) {
  int bid = blockIdx.x, t = threadIdx.x;
  const float* src;
  unsigned short* dst;
  if (bid < 32)       { src = ent + (size_t)bid * 16 * D_;          dst = entS + (size_t)bid * 4096; }
  else if (bid < 288) { int k = bid - 32;  src = img + (size_t)k * 16 * D_; dst = imgS + (size_t)k * 4096; }
  else if (bid < 304) { int k = bid - 288; src = Wq  + (size_t)k * 16 * D_; dst = WqS  + (size_t)k * 4096; }
  else if (bid < 336) { int k = bid - 304; src = Wkv + (size_t)k * 16 * D_; dst = WkvS + (size_t)k * 4096; }
  else                { int k = bid - 336; src = Wo  + (size_t)k * 16 * D_; dst = WoS  + (size_t)k * 4096; }
  __shared__ float rows[16][257];
  {
    int rr = t >> 5, c0 = (t & 31) * 8;  // 16 rows x 32 chunks of 8 floats
    float4 a = *(const float4*)(src + rr * D_ + c0);
    float4 b = *(const float4*)(src + rr * D_ + c0 + 4);
    rows[rr][c0 + 0] = a.x; rows[rr][c0 + 1] = a.y;
    rows[rr][c0 + 2] = a.z; rows[rr][c0 + 3] = a.w;
    rows[rr][c0 + 4] = b.x; rows[rr][c0 + 5] = b.y;
    rows[rr][c0 + 6] = b.z; rows[rr][c0 + 7] = b.w;
  }
  __syncthreads();
  int s = t >> 6, l = t & 63, r = l & 15, g = l >> 4;
  const float* rp = &rows[r][s * 32 + g * 8];
  UH8 u;
#pragma unroll
  for (int m = 0; m < 4; ++m) u.u[m] = pkrtz(rp[2 * m], rp[2 * m + 1]);
  ((f16x8*)dst)[s * 64 + l] = u.h;
}

// ---------- fused q + kv projection from fragment-swizzled inputs
// blocks [0,64): q-proj (qp fp32); [64,1088): kv-proj (kps swizzled K, vt)
__global__ __launch_bounds__(256) void gemm2(
    const unsigned short* __restrict__ entS, const unsigned short* __restrict__ WqS,
    const float* __restrict__ bq, float* __restrict__ qp,
    const unsigned short* __restrict__ imgS, const unsigned short* __restrict__ WkvS,
    const float* __restrict__ bkv, unsigned short* __restrict__ kps,
    unsigned short* __restrict__ vt) {
  int bid = blockIdx.x;
  int t = threadIdx.x, w = t >> 6, l = t & 63;
  int r = l & 15, g = l >> 4;
  if (bid < 64) {
    int nt = bid & 3, mg = bid >> 2;  // 32 rows per mg
    const f16x8* A = (const f16x8*)entS;
    const f16x8* Bf = (const f16x8*)WqS;
    int tA0 = mg * 2, tB = nt * 4 + w;
    f16x8 a0[8], a1[8], bf[8];
#pragma unroll
    for (int s = 0; s < 8; ++s) {
      a0[s] = A[(tA0 * 8 + s) * 64 + l];
      a1[s] = A[((tA0 + 1) * 8 + s) * 64 + l];
      bf[s] = Bf[(tB * 8 + s) * 64 + l];
    }
    f32x4 acc0 = {0.f, 0.f, 0.f, 0.f}, acc1 = {0.f, 0.f, 0.f, 0.f};
#pragma unroll
    for (int s = 0; s < 8; ++s) {
      acc0 = __builtin_amdgcn_mfma_f32_16x16x32_f16(a0[s], bf[s], acc0, 0, 0, 0);
      acc1 = __builtin_amdgcn_mfma_f32_16x16x32_f16(a1[s], bf[s], acc1, 0, 0, 0);
    }
    int n = nt * 64 + w * 16 + r;
    float bb = bq[n];
    int m0 = mg * 32;
#pragma unroll
    for (int rr = 0; rr < 4; ++rr) {
      qp[(size_t)(m0 + g * 4 + rr) * D_ + n] = acc0[rr] + bb;
      qp[(size_t)(m0 + 16 + g * 4 + rr) * D_ + n] = acc1[rr] + bb;
    }
  } else {
    int bid2 = bid - 64;
    int nt = bid2 & 7, mg = (bid2 >> 3) & 63, b = bid2 >> 9;
    const f16x8* A = (const f16x8*)imgS;
    const f16x8* Bf = (const f16x8*)WkvS;
    int tA0 = b * 128 + mg * 2, tB = nt * 4 + w;
    f16x8 a0[8], a1[8], bf[8];
#pragma unroll
    for (int s = 0; s < 8; ++s) {
      a0[s] = A[(tA0 * 8 + s) * 64 + l];
      a1[s] = A[((tA0 + 1) * 8 + s) * 64 + l];
      bf[s] = Bf[(tB * 8 + s) * 64 + l];
    }
    f32x4 acc0 = {0.f, 0.f, 0.f, 0.f}, acc1 = {0.f, 0.f, 0.f, 0.f};
#pragma unroll
    for (int s = 0; s < 8; ++s) {
      acc0 = __builtin_amdgcn_mfma_f32_16x16x32_f16(a0[s], bf[s], acc0, 0, 0, 0);
      acc1 = __builtin_amdgcn_mfma_f32_16x16x32_f16(a1[s], bf[s], acc1, 0, 0, 0);
    }
    int n = nt * 64 + w * 16 + r;
    float bb = bkv[n];
#pragma unroll
    for (int mi = 0; mi < 2; ++mi) {
      f32x4 ac = (mi == 0) ? acc0 : acc1;
      int mt = mg * 2 + mi;
      if (n < 256) {
        int s2 = n >> 5, gg = (n >> 3) & 3, e = n & 7;
        size_t base = ((size_t)((b * 128 + mt) * 8 + s2) * 64 + gg * 16) * 8 + e;
#pragma unroll
        for (int rr = 0; rr < 4; ++rr)
          kps[base + (size_t)(g * 4 + rr) * 8] = f16bits(ac[rr] + bb);
      } else {
        int c = n - 256, h = c >> 5, dd = c & 31;
        ushortv4 p;
#pragma unroll
        for (int rr = 0; rr < 4; ++rr) p[rr] = f16bits(ac[rr] + bb);
        *(ushortv4*)(vt + ((size_t)(b * H_ + h) * HD_ + dd) * KL + mt * 16 + g * 4) = p;
      }
    }
  }
}

// ---------- logits/P = exp(QK^T*scale + CPB - chunkmax) + per-chunk stats
// block = (b, 2 q-rows, 128 k), 256 threads (4 waves); wave w -> 32-k chunk.
// kf fragments fully preloaded (16 in-flight 1KB wave-loads).
__global__ __launch_bounds__(256, 4) void logits_cpb(
    const float* __restrict__ qp, const unsigned short* __restrict__ kps,
    const float* __restrict__ rd, const float* __restrict__ W1,
    const float* __restrict__ b1, const float* __restrict__ W2,
    const float* __restrict__ b2, unsigned short* __restrict__ lgb,
    float* __restrict__ stats) {
  int gid = blockIdx.x;
  int kcg = gid & 15, qg = (gid >> 4) & 127, b = gid >> 11;
  int t = threadIdx.x;
  __shared__ unsigned int w1xs[128], w1ys[128], b1ps[128];  // half2-packed
  __shared__ unsigned short w2h[H_][264];
  __shared__ unsigned int qs[2][128];  // packed scaled q pairs per q-row
  __shared__ float b2s[H_];
  if (t < 128) {
    float4 wr = *(const float4*)(W1 + 4 * t);  // rows 2t, 2t+1 of W1[256][2]
    w1xs[t] = pkrtz(wr.x, wr.z);
    w1ys[t] = pkrtz(wr.y, wr.w);
    float2 bb = *(const float2*)(b1 + 2 * t);
    b1ps[t] = pkrtz(bb.x, bb.y);
  }
#pragma unroll
  for (int i = 0; i < 2; ++i) {  // all 8 heads (256 thr x 2 = 8h x 64 float4)
    int idx = t + i * 256;
    int h = idx >> 6, c0 = (idx & 63) * 4;
    float4 wv = *(const float4*)(W2 + h * CH_ + c0);
    w2h[h][c0 + 0] = f16bits(wv.x);
    w2h[h][c0 + 1] = f16bits(wv.y);
    w2h[h][c0 + 2] = f16bits(wv.z);
    w2h[h][c0 + 3] = f16bits(wv.w);
  }
  const float scale = 0.17677669529663687f;  // 1/sqrt(32)
  {
    int q = t >> 7, j = t & 127;  // 2q x 128 = 256
    float2 v = *(const float2*)(qp + ((size_t)(b * Q_ + qg * 2 + q) * D_) + 2 * j);
    qs[q][j] = pkrtz(v.x * scale, v.y * scale);
  }
  if (t < 8) b2s[t] = b2[t];
  __syncthreads();

  int l = t & 63, w = t >> 6;
  int hp = l & 15, g = l >> 4, hq = hp & 7;
  int k0 = kcg * 128 + w * 32;
  int kt0 = k0 >> 4;
  int cc = kcg * 4 + w;  // 32-k chunk id (0..63)

  // preload ALL kf fragments (16 independent contiguous wave-loads)
  const f16x8* kb = (const f16x8*)kps + ((size_t)(b * 128 + kt0) * 8) * 64 + l;
  f16x8 kf[2][8];
#pragma unroll
  for (int r = 0; r < 2; ++r)
#pragma unroll
    for (int s = 0; s < 8; ++s) kf[r][s] = kb[(r * 8 + s) * 64];

  // rd loads + f16 packing (x broadcast pairs)
  unsigned int x2[2][2], y2[2][2];
#pragma unroll
  for (int q = 0; q < 2; ++q) {
    const float* rdb = rd + ((size_t)(b * Q_ + qg * 2 + q) * KL) * 2;
#pragma unroll
    for (int r = 0; r < 2; ++r) {
      float2 p = *(const float2*)(rdb + (k0 + r * 16 + hp) * 2);
      x2[q][r] = pkrtz(p.x, p.x);
      y2[q][r] = pkrtz(p.y, p.y);
    }
  }

  f32x4 acc[2][2];
#pragma unroll
  for (int q = 0; q < 2; ++q)
#pragma unroll
    for (int r = 0; r < 2; ++r) acc[q][r] = (f32x4){0.f, 0.f, 0.f, 0.f};

#pragma unroll
  for (int s = 0; s < 8; ++s) {
    int pidx = g * 4 + 16 * s;  // half2-pair index
    uintv4 wx = *(const uintv4*)&w1xs[pidx];
    uintv4 wy = *(const uintv4*)&w1ys[pidx];
    uintv4 bp = *(const uintv4*)&b1ps[pidx];
    f16x8 w2f = *(const f16x8*)&w2h[hq][g * 8 + 32 * s];
    bool sel = (hp == s);
#pragma unroll
    for (int q = 0; q < 2; ++q) {
      uintv4 qv = *(const uintv4*)&qs[q][s * 16 + g * 4];
      UH8 bq;
#pragma unroll
      for (int m = 0; m < 4; ++m) bq.u[m] = sel ? qv[m] : 0u;
#pragma unroll
      for (int r = 0; r < 2; ++r) {
        UH8 az;
#pragma unroll
        for (int m = 0; m < 4; ++m)
          az.u[m] = pk_max0(pk_fma(x2[q][r], wx[m], pk_fma(y2[q][r], wy[m], bp[m])));
        acc[q][r] = __builtin_amdgcn_mfma_f32_16x16x32_f16(az.h, w2f, acc[q][r], 0, 0, 0);
        acc[q][r] = __builtin_amdgcn_mfma_f32_16x16x32_f16(kf[r][s], bq.h, acc[q][r], 0, 0, 0);
      }
    }
  }

  // per-(q, chunk) epilogue: +b2, chunk max, exp, sum; store P=exp(l-mx) f16
  float bhv = b2s[hq];
#pragma unroll
  for (int q = 0; q < 2; ++q) {
    int qrow = qg * 2 + q;
    float mx = -3.0e38f;
#pragma unroll
    for (int r = 0; r < 2; ++r)
#pragma unroll
      for (int rr = 0; rr < 4; ++rr) {
        acc[q][r][rr] += bhv;
        mx = fmaxf(mx, acc[q][r][rr]);
      }
    mx = fmaxf(mx, __shfl_xor(mx, 16));
    mx = fmaxf(mx, __shfl_xor(mx, 32));
    float ex[2][4];
    float ss = 0.f;
#pragma unroll
    for (int r = 0; r < 2; ++r)
#pragma unroll
      for (int rr = 0; rr < 4; ++rr) {
        ex[r][rr] = __expf(acc[q][r][rr] - mx);
        ss += ex[r][rr];
      }
    ss += __shfl_xor(ss, 16);
    ss += __shfl_xor(ss, 32);
    if (l < 8)
      *(float2*)(stats + (((size_t)(b * H_ + l) * Q_ + qrow) * 64 + cc) * 2) =
          make_float2(mx, ss);
    if (hp < 8) {
      unsigned short* ob = lgb + ((size_t)(b * H_ + hp) * Q_ + qrow) * KL + k0;
#pragma unroll
      for (int r = 0; r < 2; ++r) {
        uint2 pk;
        pk.x = pkrtz(ex[r][0], ex[r][1]);
        pk.y = pkrtz(ex[r][2], ex[r][3]);
        *(uint2*)(ob + r * 16 + g * 4) = pk;
      }
    }
  }
}

// ---------- fused softmax-finish + PV: block = (bh, qt), 512 threads.
// lgb holds P=exp(l - chunkmax); scale by exp(chunkmax - M) from LDS, 1/S at end.
__global__ __launch_bounds__(512) void sm_pv(const unsigned short* __restrict__ lgb,
                                             const float* __restrict__ stats,
                                             const unsigned short* __restrict__ vt,
                                             unsigned short* __restrict__ ctxb) {
  int gid = blockIdx.x;
  int qt = gid & 15, bh = gid >> 4;
  int t = threadIdx.x;
  __shared__ float Ss[16];
  __shared__ float scl[16][65];
  __shared__ float pacc[8][16][33];

  {
    int row = t >> 5, cc = t & 31;
    const float2* sp = (const float2*)stats + ((size_t)bh * Q_ + qt * 16 + row) * 64;
    float2 s0 = sp[cc], s1 = sp[cc + 32];
    float m = fmaxf(s0.x, s1.x);
#pragma unroll
    for (int off = 16; off > 0; off >>= 1) m = fmaxf(m, __shfl_xor(m, off));
    float c0 = __expf(s0.x - m), c1 = __expf(s1.x - m);
    float e = s0.y * c0 + s1.y * c1;
#pragma unroll
    for (int off = 16; off > 0; off >>= 1) e += __shfl_xor(e, off);
    scl[row][cc] = c0;
    scl[row][cc + 32] = c1;
    if (cc == 0) Ss[row] = 1.0f / e;
  }
  __syncthreads();

  int l = t & 63, w = t >> 6;
  int qq = l & 15, g = l >> 4;
  const unsigned short* lr2 =
      lgb + ((size_t)bh * Q_ + qt * 16 + qq) * KL + w * 256 + g * 8;
  const unsigned short* vb0 =
      vt + ((size_t)bh * HD_ + qq) * KL + w * 256 + g * 8;
  const unsigned short* vb1 = vb0 + (size_t)16 * KL;
  f32x4 a0 = {0.f, 0.f, 0.f, 0.f}, a1 = {0.f, 0.f, 0.f, 0.f};
#pragma unroll
  for (int step = 0; step < 8; ++step) {
    UH8 raw = *(const UH8*)(lr2 + step * 32);
    float sc = scl[qq][w * 8 + step];
    unsigned int sc2 = pkrtz(sc, sc);
    UH8 pa;
#pragma unroll
    for (int mI = 0; mI < 4; ++mI) pa.u[mI] = pk_mul(raw.u[mI], sc2);
    f16x8 v0 = *(const f16x8*)(vb0 + step * 32);
    f16x8 v1 = *(const f16x8*)(vb1 + step * 32);
    a0 = __builtin_amdgcn_mfma_f32_16x16x32_f16(pa.h, v0, a0, 0, 0, 0);
    a1 = __builtin_amdgcn_mfma_f32_16x16x32_f16(pa.h, v1, a1, 0, 0, 0);
  }
#pragma unroll
  for (int rr = 0; rr < 4; ++rr) {
    pacc[w][g * 4 + rr][qq] = a0[rr];
    pacc[w][g * 4 + rr][qq + 16] = a1[rr];
  }
  __syncthreads();

  {
    int qo = t >> 5, dd = t & 31;
    float sum = 0.f;
#pragma unroll
    for (int wv = 0; wv < 8; ++wv) sum += pacc[wv][qo][dd];
    sum *= Ss[qo];
    int b = bh >> 3, h = bh & 7;
    ctxb[((size_t)b * Q_ + qt * 16 + qo) * D_ + h * HD_ + dd] = f16bits(sum);
  }
}

// ---------- out projection: out = ctxb(f16) @ Wo^T + bo (fp32 out)
__global__ __launch_bounds__(256) void gemm_o(const unsigned short* __restrict__ A,
                                              const unsigned short* __restrict__ WoS,
                                              const float* __restrict__ bias,
                                              float* __restrict__ out) {
  int nt = blockIdx.x & 3, mt = blockIdx.x >> 2;
  int t = threadIdx.x, w = t >> 6, l = t & 63;
  int m0 = mt * 16;
  int r = l & 15, g = l >> 4;
  const unsigned short* arow = A + (size_t)(m0 + r) * D_;
  int tB = nt * 4 + w;
  f16x8 af[8], bf[8];
#pragma unroll
  for (int s = 0; s < 8; ++s) {
    af[s] = *(const f16x8*)(arow + s * 32 + g * 8);
    bf[s] = ((const f16x8*)WoS)[(tB * 8 + s) * 64 + l];
  }
  f32x4 acc = {0.f, 0.f, 0.f, 0.f};
#pragma unroll
  for (int s = 0; s < 8; ++s)
    acc = __builtin_amdgcn_mfma_f32_16x16x32_f16(af[s], bf[s], acc, 0, 0, 0);
  int n = nt * 64 + w * 16 + r;
  float bb = bias[n];
#pragma unroll
  for (int rr = 0; rr < 4; ++rr)
    out[(size_t)(m0 + g * 4 + rr) * D_ + n] = acc[rr] + bb;
}

extern "C" void kernel_launch(void* const* d_in, const int* in_sizes, int n_in,
                              void* d_out, int out_size, void* d_ws, size_t ws_size,
                              hipStream_t stream) {
  const float* ent  = (const float*)d_in[0];
  const float* img  = (const float*)d_in[1];
  const float* rd   = (const float*)d_in[2];
  const float* Wq   = (const float*)d_in[3];
  const float* bq   = (const float*)d_in[4];
  const float* Wkv  = (const float*)d_in[5];
  const float* bkv  = (const float*)d_in[6];
  const float* W1   = (const float*)d_in[7];
  const float* b1   = (const float*)d_in[8];
  const float* W2   = (const float*)d_in[9];
  const float* b2   = (const float*)d_in[10];
  const float* Wo   = (const float*)d_in[11];
  const float* bo   = (const float*)d_in[12];
  float* out = (float*)d_out;

  char* ws = (char*)d_ws;
  float*          qp    = (float*)(ws + 0);                  //   524,288 fp32 [b][q][c]
  unsigned short* kps   = (unsigned short*)(ws + 524288);    // 2,097,152 f16 swizzled K
  unsigned short* vt    = (unsigned short*)(ws + 2621440);   // 2,097,152 f16 [b][h][dd][k]
  unsigned short* lgb   = (unsigned short*)(ws + 4718592);   // 16,777,216 f16 P-chunks
  float*          stats = (float*)(ws + 21495808);           // 2,097,152 float2 [b][h][q][cc64]
  unsigned short* ctxb  = (unsigned short*)(ws + 23592960);  //   262,144 f16 [b][q][c]
  unsigned short* entS  = (unsigned short*)(ws + 23855104);  //   262,144 f16 frag
  unsigned short* imgS  = (unsigned short*)(ws + 24117248);  // 2,097,152 f16 frag
  unsigned short* WqS   = (unsigned short*)(ws + 26214400);  //   131,072 f16 frag
  unsigned short* WkvS  = (unsigned short*)(ws + 26345472);  //   262,144 f16 frag
  unsigned short* WoS   = (unsigned short*)(ws + 26607616);  //   131,072 f16 frag

  prep<<<dim3(352), dim3(512), 0, stream>>>(ent, img, Wq, Wkv, Wo,
                                            entS, imgS, WqS, WkvS, WoS);
  gemm2<<<dim3(64 + 1024), dim3(256), 0, stream>>>(entS, WqS, bq, qp,
                                                   imgS, WkvS, bkv, kps, vt);
  logits_cpb<<<dim3(B_ * 128 * 16), dim3(256), 0, stream>>>(qp, kps, rd, W1, b1, W2, b2, lgb, stats);
  sm_pv<<<dim3(B_ * H_ * 16), dim3(512), 0, stream>>>(lgb, stats, vt, ctxb);
  gemm_o<<<dim3(128), dim3(256), 0, stream>>>(ctxb, WoS, bo, out);
}

// Round 15
// 54.803 us; speedup vs baseline: 1.1191x; 1.1191x over previous
//
#include <hip/hip_runtime.h>
#include <hip/hip_bf16.h>
#include <cstdint>
#include <cstddef>

#define B_  2
#define Q_  256
#define KL  2048
#define D_  256
#define H_  8
#define HD_ 32
#define CH_ 256

typedef _Float16 f16;
typedef __fp16 fp16x2 __attribute__((ext_vector_type(2)));
typedef _Float16 f16x8 __attribute__((ext_vector_type(8)));
typedef unsigned short ushortv4 __attribute__((ext_vector_type(4)));
typedef unsigned int uintv4 __attribute__((ext_vector_type(4)));
typedef float f32x4 __attribute__((ext_vector_type(4)));

union UH  { fp16x2 h; unsigned int u; };
union UH8 { f16x8 h; unsigned int u[4]; };

__device__ __forceinline__ unsigned int pkrtz(float a, float b) {
  UH r; r.h = __builtin_amdgcn_cvt_pkrtz(a, b); return r.u;
}
__device__ __forceinline__ unsigned short f16bits(float a) {
  return (unsigned short)(pkrtz(a, 0.f) & 0xffffu);
}
__device__ __forceinline__ float h2f(unsigned short u) {
  __fp16 h = *(__fp16*)&u;
  return (float)h;
}
__device__ __forceinline__ unsigned int pk_fma(unsigned int a, unsigned int b,
                                               unsigned int c) {
  unsigned int d;
  asm("v_pk_fma_f16 %0, %1, %2, %3" : "=v"(d) : "v"(a), "v"(b), "v"(c));
  return d;
}
__device__ __forceinline__ unsigned int pk_max0(unsigned int a) {
  unsigned int d;
  asm("v_pk_max_f16 %0, %1, %2" : "=v"(d) : "v"(a), "v"(0u));
  return d;
}

// ---------- prep: fp32 row-major -> f16 MFMA-fragment layout
// ((f16x8*)dst)[(tile*8+s)*64 + lane] = src[tile*16+(l&15)][s*32+(l>>4)*8 ..+8]
__global__ __launch_bounds__(512) void prep(
    const float* __restrict__ ent, const float* __restrict__ img,
    const float* __restrict__ Wq, const float* __restrict__ Wkv,
    const float* __restrict__ Wo,
    unsigned short* __restrict__ entS, unsigned short* __restrict__ imgS,
    unsigned short* __restrict__ WqS, unsigned short* __restrict__ WkvS,
    unsigned short* __restrict__ WoS) {
  int bid = blockIdx.x, t = threadIdx.x;
  const float* src;
  unsigned short* dst;
  if (bid < 32)       { src = ent + (size_t)bid * 16 * D_;          dst = entS + (size_t)bid * 4096; }
  else if (bid < 288) { int k = bid - 32;  src = img + (size_t)k * 16 * D_; dst = imgS + (size_t)k * 4096; }
  else if (bid < 304) { int k = bid - 288; src = Wq  + (size_t)k * 16 * D_; dst = WqS  + (size_t)k * 4096; }
  else if (bid < 336) { int k = bid - 304; src = Wkv + (size_t)k * 16 * D_; dst = WkvS + (size_t)k * 4096; }
  else                { int k = bid - 336; src = Wo  + (size_t)k * 16 * D_; dst = WoS  + (size_t)k * 4096; }
  __shared__ float rows[16][257];
  {
    int rr = t >> 5, c0 = (t & 31) * 8;
    float4 a = *(const float4*)(src + rr * D_ + c0);
    float4 b = *(const float4*)(src + rr * D_ + c0 + 4);
    rows[rr][c0 + 0] = a.x; rows[rr][c0 + 1] = a.y;
    rows[rr][c0 + 2] = a.z; rows[rr][c0 + 3] = a.w;
    rows[rr][c0 + 4] = b.x; rows[rr][c0 + 5] = b.y;
    rows[rr][c0 + 6] = b.z; rows[rr][c0 + 7] = b.w;
  }
  __syncthreads();
  int s = t >> 6, l = t & 63, r = l & 15, g = l >> 4;
  const float* rp = &rows[r][s * 32 + g * 8];
  UH8 u;
#pragma unroll
  for (int m = 0; m < 4; ++m) u.u[m] = pkrtz(rp[2 * m], rp[2 * m + 1]);
  ((f16x8*)dst)[s * 64 + l] = u.h;
}

// ---------- fused q + kv projection
// blocks [0,64): q-proj -> qpf f16 fragments (scale folded)
// qpf[(qt_g*8 + h)*512 + ((c>>3&3)*16 + row&15)*8 + (c&7)] = q_scaled[row][h*32+c]
// blocks [64,1088): kv-proj -> kps swizzled K, vt [b][h][dd][k]
__global__ __launch_bounds__(256) void gemm2(
    const unsigned short* __restrict__ entS, const unsigned short* __restrict__ WqS,
    const float* __restrict__ bq, unsigned short* __restrict__ qpf,
    const unsigned short* __restrict__ imgS, const unsigned short* __restrict__ WkvS,
    const float* __restrict__ bkv, unsigned short* __restrict__ kps,
    unsigned short* __restrict__ vt) {
  int bid = blockIdx.x;
  int t = threadIdx.x, w = t >> 6, l = t & 63;
  int r = l & 15, g = l >> 4;
  const float scale = 0.17677669529663687f;  // 1/sqrt(32)
  if (bid < 64) {
    int nt = bid & 3, mg = bid >> 2;
    const f16x8* A = (const f16x8*)entS;
    const f16x8* Bf = (const f16x8*)WqS;
    int tA0 = mg * 2, tB = nt * 4 + w;
    f16x8 a0[8], a1[8], bf[8];
#pragma unroll
    for (int s = 0; s < 8; ++s) {
      a0[s] = A[(tA0 * 8 + s) * 64 + l];
      a1[s] = A[((tA0 + 1) * 8 + s) * 64 + l];
      bf[s] = Bf[(tB * 8 + s) * 64 + l];
    }
    f32x4 acc0 = {0.f, 0.f, 0.f, 0.f}, acc1 = {0.f, 0.f, 0.f, 0.f};
#pragma unroll
    for (int s = 0; s < 8; ++s) {
      acc0 = __builtin_amdgcn_mfma_f32_16x16x32_f16(a0[s], bf[s], acc0, 0, 0, 0);
      acc1 = __builtin_amdgcn_mfma_f32_16x16x32_f16(a1[s], bf[s], acc1, 0, 0, 0);
    }
    int n = nt * 64 + w * 16 + r;
    float bb = bq[n];
    int h = n >> 5, gq = (n >> 3) & 3, e = n & 7;
    int m0 = mg * 32;
#pragma unroll
    for (int half = 0; half < 2; ++half) {
      f32x4 ac = half ? acc1 : acc0;
#pragma unroll
      for (int rr = 0; rr < 4; ++rr) {
        int row = m0 + half * 16 + g * 4 + rr;
        int qt_g = row >> 4, rq = row & 15;
        qpf[((size_t)(qt_g * 8 + h)) * 512 + (gq * 16 + rq) * 8 + e] =
            f16bits((ac[rr] + bb) * scale);
      }
    }
  } else {
    int bid2 = bid - 64;
    int nt = bid2 & 7, mg = (bid2 >> 3) & 63, b = bid2 >> 9;
    const f16x8* A = (const f16x8*)imgS;
    const f16x8* Bf = (const f16x8*)WkvS;
    int tA0 = b * 128 + mg * 2, tB = nt * 4 + w;
    f16x8 a0[8], a1[8], bf[8];
#pragma unroll
    for (int s = 0; s < 8; ++s) {
      a0[s] = A[(tA0 * 8 + s) * 64 + l];
      a1[s] = A[((tA0 + 1) * 8 + s) * 64 + l];
      bf[s] = Bf[(tB * 8 + s) * 64 + l];
    }
    f32x4 acc0 = {0.f, 0.f, 0.f, 0.f}, acc1 = {0.f, 0.f, 0.f, 0.f};
#pragma unroll
    for (int s = 0; s < 8; ++s) {
      acc0 = __builtin_amdgcn_mfma_f32_16x16x32_f16(a0[s], bf[s], acc0, 0, 0, 0);
      acc1 = __builtin_amdgcn_mfma_f32_16x16x32_f16(a1[s], bf[s], acc1, 0, 0, 0);
    }
    int n = nt * 64 + w * 16 + r;
    float bb = bkv[n];
#pragma unroll
    for (int mi = 0; mi < 2; ++mi) {
      f32x4 ac = (mi == 0) ? acc0 : acc1;
      int mt = mg * 2 + mi;
      if (n < 256) {
        int s2 = n >> 5, gg = (n >> 3) & 3, e = n & 7;
        size_t base = ((size_t)((b * 128 + mt) * 8 + s2) * 64 + gg * 16) * 8 + e;
#pragma unroll
        for (int rr = 0; rr < 4; ++rr)
          kps[base + (size_t)(g * 4 + rr) * 8] = f16bits(ac[rr] + bb);
      } else {
        int c = n - 256, h = c >> 5, dd = c & 31;
        ushortv4 p;
#pragma unroll
        for (int rr = 0; rr < 4; ++rr) p[rr] = f16bits(ac[rr] + bb);
        *(ushortv4*)(vt + ((size_t)(b * H_ + h) * HD_ + dd) * KL + mt * 16 + g * 4) = p;
      }
    }
  }
}

// ---------- cpb: z-MLP + W2 MFMA only; out = cpb4 fragment layout (no b2)
// cpb4 tile T = ((b*8+h)*128 + kt)*16 + qt; elem [lane*4 + rr] f16
// block = (b, 2 q-rows, 128 k), 256 threads / 4 waves
__global__ __launch_bounds__(256, 8) void cpb_k(
    const float* __restrict__ rd, const float* __restrict__ W1,
    const float* __restrict__ b1, const float* __restrict__ W2,
    unsigned short* __restrict__ cpb4) {
  int gid = blockIdx.x;
  int kcg = gid & 15, qg = (gid >> 4) & 127, b = gid >> 11;
  int t = threadIdx.x;
  __shared__ unsigned int w1xs[128], w1ys[128], b1ps[128];
  __shared__ unsigned short w2h[H_][264];
  if (t < 128) {
    float4 wr = *(const float4*)(W1 + 4 * t);
    w1xs[t] = pkrtz(wr.x, wr.z);
    w1ys[t] = pkrtz(wr.y, wr.w);
    float2 bb = *(const float2*)(b1 + 2 * t);
    b1ps[t] = pkrtz(bb.x, bb.y);
  }
#pragma unroll
  for (int i = 0; i < 2; ++i) {
    int idx = t + i * 256;
    int h = idx >> 6, c0 = (idx & 63) * 4;
    float4 wv = *(const float4*)(W2 + h * CH_ + c0);
    w2h[h][c0 + 0] = f16bits(wv.x);
    w2h[h][c0 + 1] = f16bits(wv.y);
    w2h[h][c0 + 2] = f16bits(wv.z);
    w2h[h][c0 + 3] = f16bits(wv.w);
  }
  __syncthreads();

  int l = t & 63, w = t >> 6;
  int hp = l & 15, g = l >> 4, hq = hp & 7;
  int k0 = kcg * 128 + w * 32;
  int kt0 = k0 >> 4;

  unsigned int x2[2][2], y2[2][2];
#pragma unroll
  for (int q = 0; q < 2; ++q) {
    const float* rdb = rd + ((size_t)(b * Q_ + qg * 2 + q) * KL) * 2;
#pragma unroll
    for (int r = 0; r < 2; ++r) {
      float2 p = *(const float2*)(rdb + (k0 + r * 16 + hp) * 2);
      x2[q][r] = pkrtz(p.x, p.x);
      y2[q][r] = pkrtz(p.y, p.y);
    }
  }

  f32x4 acc[2][2];
#pragma unroll
  for (int q = 0; q < 2; ++q)
#pragma unroll
    for (int r = 0; r < 2; ++r) acc[q][r] = (f32x4){0.f, 0.f, 0.f, 0.f};

#pragma unroll
  for (int s = 0; s < 8; ++s) {
    int pidx = g * 4 + 16 * s;
    uintv4 wx = *(const uintv4*)&w1xs[pidx];
    uintv4 wy = *(const uintv4*)&w1ys[pidx];
    uintv4 bp = *(const uintv4*)&b1ps[pidx];
    f16x8 w2f = *(const f16x8*)&w2h[hq][g * 8 + 32 * s];
#pragma unroll
    for (int q = 0; q < 2; ++q)
#pragma unroll
      for (int r = 0; r < 2; ++r) {
        UH8 az;
#pragma unroll
        for (int m = 0; m < 4; ++m)
          az.u[m] = pk_max0(pk_fma(x2[q][r], wx[m], pk_fma(y2[q][r], wy[m], bp[m])));
        acc[q][r] = __builtin_amdgcn_mfma_f32_16x16x32_f16(az.h, w2f, acc[q][r], 0, 0, 0);
      }
  }

  if (hp < 8) {
#pragma unroll
    for (int q = 0; q < 2; ++q) {
      int qrow = qg * 2 + q;
      int qt = qrow >> 4, qc = qrow & 15;
#pragma unroll
      for (int r = 0; r < 2; ++r) {
        size_t T = ((size_t)(b * 8 + hp) * 128 + kt0 + r) * 16 + qt;
        uint2 pk;
        pk.x = pkrtz(acc[q][r][0], acc[q][r][1]);
        pk.y = pkrtz(acc[q][r][2], acc[q][r][3]);
        *(uint2*)(cpb4 + T * 256 + (g * 16 + qc) * 4) = pk;
      }
    }
  }
}

// ---------- attn: dense QK (+cpb as C) + exact softmax + PV
// block = ((b*8+h)*16 + qt), 512 threads / 8 waves; wave w -> k in [w*256, +256)
__global__ __launch_bounds__(512) void attn(
    const unsigned short* __restrict__ qpf, const unsigned short* __restrict__ kps,
    const unsigned short* __restrict__ cpb4, const unsigned short* __restrict__ vt,
    unsigned short* __restrict__ ctxb) {
  int gid = blockIdx.x;
  int qt = gid & 15, bh = gid >> 4;
  int b = bh >> 3, h = bh & 7;
  int t = threadIdx.x, w = t >> 6, l = t & 63;
  int qq = l & 15, g = l >> 4;
  __shared__ unsigned short Plds[8][16][256];  // 64 KB, XOR-swizzled rows
  __shared__ float wred[8][16];
  __shared__ float pacc[8][16][33];

  // q B-fragment (scale already folded)
  UH8 qB;
  {
    const unsigned int* qpu = (const unsigned int*)qpf;
    uintv4 qv = *(const uintv4*)(qpu + ((size_t)((b * 16 + qt) * 8 + h)) * 256 + l * 4);
#pragma unroll
    for (int m = 0; m < 4; ++m) qB.u[m] = qv[m];
  }

  // QK: 16 tiles, C-init = cpb
  const f16x8* ka = (const f16x8*)kps + ((size_t)(b * 128) * 8) * 64 + l;
  const unsigned short* cb = cpb4 + ((size_t)bh * 128 * 16 + qt) * 256 + l * 4;
  f32x4 S[16];
#pragma unroll
  for (int i = 0; i < 16; ++i) {
    int kt = w * 16 + i;
    uint2 c2 = *(const uint2*)(cb + (size_t)kt * 4096);
    f32x4 C;
    C[0] = h2f((unsigned short)(c2.x & 0xffff));
    C[1] = h2f((unsigned short)(c2.x >> 16));
    C[2] = h2f((unsigned short)(c2.y & 0xffff));
    C[3] = h2f((unsigned short)(c2.y >> 16));
    f16x8 af = ka[((size_t)kt * 8 + h) * 64];
    S[i] = __builtin_amdgcn_mfma_f32_16x16x32_f16(af, qB.h, C, 0, 0, 0);
  }

  // block max per q-col
  float m = -3.0e38f;
#pragma unroll
  for (int i = 0; i < 16; ++i)
#pragma unroll
    for (int rr = 0; rr < 4; ++rr) m = fmaxf(m, S[i][rr]);
  m = fmaxf(m, __shfl_xor(m, 16));
  m = fmaxf(m, __shfl_xor(m, 32));
  if (l < 16) wred[w][l] = m;
  __syncthreads();
  float M = wred[0][qq];
#pragma unroll
  for (int wv = 1; wv < 8; ++wv) M = fmaxf(M, wred[wv][qq]);
  __syncthreads();  // all reads of wred done before reuse

  // exp + P_lds (per-wave region, XOR swizzle byte^=(q&7)<<4) + sum
  float ss = 0.f;
  char* prow = (char*)&Plds[w][qq][0];
  int xr = (qq & 7) << 4;
#pragma unroll
  for (int i = 0; i < 16; ++i) {
    float p0 = __expf(S[i][0] - M);
    float p1 = __expf(S[i][1] - M);
    float p2 = __expf(S[i][2] - M);
    float p3 = __expf(S[i][3] - M);
    ss += (p0 + p1) + (p2 + p3);
    uint2 pk;
    pk.x = pkrtz(p0, p1);
    pk.y = pkrtz(p2, p3);
    *(uint2*)(prow + ((i * 32 + g * 8) ^ xr)) = pk;
  }
  ss += __shfl_xor(ss, 16);
  ss += __shfl_xor(ss, 32);
  if (l < 16) wred[w][l] = ss;

  // PV over own 256-k range
  const unsigned short* vb0 = vt + ((size_t)bh * HD_ + qq) * KL + w * 256 + g * 8;
  const unsigned short* vb1 = vb0 + (size_t)16 * KL;
  f32x4 a0 = {0.f, 0.f, 0.f, 0.f}, a1 = {0.f, 0.f, 0.f, 0.f};
#pragma unroll
  for (int cw = 0; cw < 8; ++cw) {
    f16x8 pa = *(const f16x8*)(prow + ((cw * 64 + g * 16) ^ xr));
    f16x8 v0 = *(const f16x8*)(vb0 + cw * 32);
    f16x8 v1 = *(const f16x8*)(vb1 + cw * 32);
    a0 = __builtin_amdgcn_mfma_f32_16x16x32_f16(pa, v0, a0, 0, 0, 0);
    a1 = __builtin_amdgcn_mfma_f32_16x16x32_f16(pa, v1, a1, 0, 0, 0);
  }
#pragma unroll
  for (int rr = 0; rr < 4; ++rr) {
    pacc[w][g * 4 + rr][qq] = a0[rr];
    pacc[w][g * 4 + rr][qq + 16] = a1[rr];
  }
  __syncthreads();

  {
    int qo = t >> 5, dd = t & 31;
    float sum = 0.f, st = 0.f;
#pragma unroll
    for (int wv = 0; wv < 8; ++wv) {
      sum += pacc[wv][qo][dd];
      st += wred[wv][qo];
    }
    ctxb[((size_t)b * Q_ + qt * 16 + qo) * D_ + h * HD_ + dd] = f16bits(sum / st);
  }
}

// ---------- out projection: out = ctxb(f16) @ Wo^T + bo (fp32 out)
__global__ __launch_bounds__(256) void gemm_o(const unsigned short* __restrict__ A,
                                              const unsigned short* __restrict__ WoS,
                                              const float* __restrict__ bias,
                                              float* __restrict__ out) {
  int nt = blockIdx.x & 3, mt = blockIdx.x >> 2;
  int t = threadIdx.x, w = t >> 6, l = t & 63;
  int m0 = mt * 16;
  int r = l & 15, g = l >> 4;
  const unsigned short* arow = A + (size_t)(m0 + r) * D_;
  int tB = nt * 4 + w;
  f16x8 af[8], bf[8];
#pragma unroll
  for (int s = 0; s < 8; ++s) {
    af[s] = *(const f16x8*)(arow + s * 32 + g * 8);
    bf[s] = ((const f16x8*)WoS)[(tB * 8 + s) * 64 + l];
  }
  f32x4 acc = {0.f, 0.f, 0.f, 0.f};
#pragma unroll
  for (int s = 0; s < 8; ++s)
    acc = __builtin_amdgcn_mfma_f32_16x16x32_f16(af[s], bf[s], acc, 0, 0, 0);
  int n = nt * 64 + w * 16 + r;
  float bb = bias[n];
#pragma unroll
  for (int rr = 0; rr < 4; ++rr)
    out[(size_t)(m0 + g * 4 + rr) * D_ + n] = acc[rr] + bb;
}

extern "C" void kernel_launch(void* const* d_in, const int* in_sizes, int n_in,
                              void* d_out, int out_size, void* d_ws, size_t ws_size,
                              hipStream_t stream) {
  const float* ent  = (const float*)d_in[0];
  const float* img  = (const float*)d_in[1];
  const float* rd   = (const float*)d_in[2];
  const float* Wq   = (const float*)d_in[3];
  const float* bq   = (const float*)d_in[4];
  const float* Wkv  = (const float*)d_in[5];
  const float* bkv  = (const float*)d_in[6];
  const float* W1   = (const float*)d_in[7];
  const float* b1   = (const float*)d_in[8];
  const float* W2   = (const float*)d_in[9];
  const float* b2   = (const float*)d_in[10];
  const float* Wo   = (const float*)d_in[11];
  const float* bo   = (const float*)d_in[12];
  float* out = (float*)d_out;
  (void)b2;  // cancels in softmax (constant per row)

  char* ws = (char*)d_ws;
  unsigned short* kps   = (unsigned short*)(ws + 0);         // 2,097,152 f16 swizzled K
  unsigned short* vt    = (unsigned short*)(ws + 2097152);   // 2,097,152 f16 [b][h][dd][k]
  unsigned short* cpb4  = (unsigned short*)(ws + 4194304);   // 16,777,216 f16 cpb fragments
  unsigned short* ctxb  = (unsigned short*)(ws + 20971520);  //   262,144 f16 [b][q][c]
  unsigned short* qpf   = (unsigned short*)(ws + 21233664);  //   262,144 f16 q fragments
  unsigned short* entS  = (unsigned short*)(ws + 21495808);  //   262,144 f16 frag
  unsigned short* imgS  = (unsigned short*)(ws + 21757952);  // 2,097,152 f16 frag
  unsigned short* WqS   = (unsigned short*)(ws + 23855104);  //   131,072 f16 frag
  unsigned short* WkvS  = (unsigned short*)(ws + 23986176);  //   262,144 f16 frag
  unsigned short* WoS   = (unsigned short*)(ws + 24248320);  //   131,072 f16 frag

  prep<<<dim3(352), dim3(512), 0, stream>>>(ent, img, Wq, Wkv, Wo,
                                            entS, imgS, WqS, WkvS, WoS);
  gemm2<<<dim3(64 + 1024), dim3(256), 0, stream>>>(entS, WqS, bq, qpf,
                                                   imgS, WkvS, bkv, kps, vt);
  cpb_k<<<dim3(B_ * 128 * 16), dim3(256), 0, stream>>>(rd, W1, b1, W2, cpb4);
  attn<<<dim3(B_ * H_ * 16), dim3(512), 0, stream>>>(qpf, kps, cpb4, vt, ctxb);
  gemm_o<<<dim3(128), dim3(256), 0, stream>>>(ctxb, WoS, bo, out);
}

// Round 16
// 54.606 us; speedup vs baseline: 1.1231x; 1.0036x over previous
//
#include <hip/hip_runtime.h>
#include <hip/hip_bf16.h>
#include <cstdint>
#include <cstddef>

#define B_  2
#define Q_  256
#define KL  2048
#define D_  256
#define H_  8
#define HD_ 32
#define CH_ 256

typedef _Float16 f16;
typedef __fp16 fp16x2 __attribute__((ext_vector_type(2)));
typedef _Float16 f16x8 __attribute__((ext_vector_type(8)));
typedef unsigned short ushortv4 __attribute__((ext_vector_type(4)));
typedef unsigned int uintv4 __attribute__((ext_vector_type(4)));
typedef float f32x4 __attribute__((ext_vector_type(4)));

union UH  { fp16x2 h; unsigned int u; };
union UH8 { f16x8 h; unsigned int u[4]; };

__device__ __forceinline__ unsigned int pkrtz(float a, float b) {
  UH r; r.h = __builtin_amdgcn_cvt_pkrtz(a, b); return r.u;
}
__device__ __forceinline__ unsigned short f16bits(float a) {
  return (unsigned short)(pkrtz(a, 0.f) & 0xffffu);
}
__device__ __forceinline__ float h2f(unsigned short u) {
  __fp16 h = *(__fp16*)&u;
  return (float)h;
}
__device__ __forceinline__ unsigned int pk_fma(unsigned int a, unsigned int b,
                                               unsigned int c) {
  unsigned int d;
  asm("v_pk_fma_f16 %0, %1, %2, %3" : "=v"(d) : "v"(a), "v"(b), "v"(c));
  return d;
}
__device__ __forceinline__ unsigned int pk_max0(unsigned int a) {
  unsigned int d;
  asm("v_pk_max_f16 %0, %1, %2" : "=v"(d) : "v"(a), "v"(0u));
  return d;
}

// ---------- prep: fp32 row-major -> f16 MFMA-fragment layout
__global__ __launch_bounds__(512) void prep(
    const float* __restrict__ ent, const float* __restrict__ img,
    const float* __restrict__ Wq, const float* __restrict__ Wkv,
    const float* __restrict__ Wo,
    unsigned short* __restrict__ entS, unsigned short* __restrict__ imgS,
    unsigned short* __restrict__ WqS, unsigned short* __restrict__ WkvS,
    unsigned short* __restrict__ WoS) {
  int bid = blockIdx.x, t = threadIdx.x;
  const float* src;
  unsigned short* dst;
  if (bid < 32)       { src = ent + (size_t)bid * 16 * D_;          dst = entS + (size_t)bid * 4096; }
  else if (bid < 288) { int k = bid - 32;  src = img + (size_t)k * 16 * D_; dst = imgS + (size_t)k * 4096; }
  else if (bid < 304) { int k = bid - 288; src = Wq  + (size_t)k * 16 * D_; dst = WqS  + (size_t)k * 4096; }
  else if (bid < 336) { int k = bid - 304; src = Wkv + (size_t)k * 16 * D_; dst = WkvS + (size_t)k * 4096; }
  else                { int k = bid - 336; src = Wo  + (size_t)k * 16 * D_; dst = WoS  + (size_t)k * 4096; }
  __shared__ float rows[16][257];
  {
    int rr = t >> 5, c0 = (t & 31) * 8;
    float4 a = *(const float4*)(src + rr * D_ + c0);
    float4 b = *(const float4*)(src + rr * D_ + c0 + 4);
    rows[rr][c0 + 0] = a.x; rows[rr][c0 + 1] = a.y;
    rows[rr][c0 + 2] = a.z; rows[rr][c0 + 3] = a.w;
    rows[rr][c0 + 4] = b.x; rows[rr][c0 + 5] = b.y;
    rows[rr][c0 + 6] = b.z; rows[rr][c0 + 7] = b.w;
  }
  __syncthreads();
  int s = t >> 6, l = t & 63, r = l & 15, g = l >> 4;
  const float* rp = &rows[r][s * 32 + g * 8];
  UH8 u;
#pragma unroll
  for (int m = 0; m < 4; ++m) u.u[m] = pkrtz(rp[2 * m], rp[2 * m + 1]);
  ((f16x8*)dst)[s * 64 + l] = u.h;
}

// ---------- fused q + kv projection (unchanged from R15)
__global__ __launch_bounds__(256) void gemm2(
    const unsigned short* __restrict__ entS, const unsigned short* __restrict__ WqS,
    const float* __restrict__ bq, unsigned short* __restrict__ qpf,
    const unsigned short* __restrict__ imgS, const unsigned short* __restrict__ WkvS,
    const float* __restrict__ bkv, unsigned short* __restrict__ kps,
    unsigned short* __restrict__ vt) {
  int bid = blockIdx.x;
  int t = threadIdx.x, w = t >> 6, l = t & 63;
  int r = l & 15, g = l >> 4;
  const float scale = 0.17677669529663687f;  // 1/sqrt(32)
  if (bid < 64) {
    int nt = bid & 3, mg = bid >> 2;
    const f16x8* A = (const f16x8*)entS;
    const f16x8* Bf = (const f16x8*)WqS;
    int tA0 = mg * 2, tB = nt * 4 + w;
    f16x8 a0[8], a1[8], bf[8];
#pragma unroll
    for (int s = 0; s < 8; ++s) {
      a0[s] = A[(tA0 * 8 + s) * 64 + l];
      a1[s] = A[((tA0 + 1) * 8 + s) * 64 + l];
      bf[s] = Bf[(tB * 8 + s) * 64 + l];
    }
    f32x4 acc0 = {0.f, 0.f, 0.f, 0.f}, acc1 = {0.f, 0.f, 0.f, 0.f};
#pragma unroll
    for (int s = 0; s < 8; ++s) {
      acc0 = __builtin_amdgcn_mfma_f32_16x16x32_f16(a0[s], bf[s], acc0, 0, 0, 0);
      acc1 = __builtin_amdgcn_mfma_f32_16x16x32_f16(a1[s], bf[s], acc1, 0, 0, 0);
    }
    int n = nt * 64 + w * 16 + r;
    float bb = bq[n];
    int h = n >> 5, gq = (n >> 3) & 3, e = n & 7;
    int m0 = mg * 32;
#pragma unroll
    for (int half = 0; half < 2; ++half) {
      f32x4 ac = half ? acc1 : acc0;
#pragma unroll
      for (int rr = 0; rr < 4; ++rr) {
        int row = m0 + half * 16 + g * 4 + rr;
        int qt_g = row >> 4, rq = row & 15;
        qpf[((size_t)(qt_g * 8 + h)) * 512 + (gq * 16 + rq) * 8 + e] =
            f16bits((ac[rr] + bb) * scale);
      }
    }
  } else {
    int bid2 = bid - 64;
    int nt = bid2 & 7, mg = (bid2 >> 3) & 63, b = bid2 >> 9;
    const f16x8* A = (const f16x8*)imgS;
    const f16x8* Bf = (const f16x8*)WkvS;
    int tA0 = b * 128 + mg * 2, tB = nt * 4 + w;
    f16x8 a0[8], a1[8], bf[8];
#pragma unroll
    for (int s = 0; s < 8; ++s) {
      a0[s] = A[(tA0 * 8 + s) * 64 + l];
      a1[s] = A[((tA0 + 1) * 8 + s) * 64 + l];
      bf[s] = Bf[(tB * 8 + s) * 64 + l];
    }
    f32x4 acc0 = {0.f, 0.f, 0.f, 0.f}, acc1 = {0.f, 0.f, 0.f, 0.f};
#pragma unroll
    for (int s = 0; s < 8; ++s) {
      acc0 = __builtin_amdgcn_mfma_f32_16x16x32_f16(a0[s], bf[s], acc0, 0, 0, 0);
      acc1 = __builtin_amdgcn_mfma_f32_16x16x32_f16(a1[s], bf[s], acc1, 0, 0, 0);
    }
    int n = nt * 64 + w * 16 + r;
    float bb = bkv[n];
#pragma unroll
    for (int mi = 0; mi < 2; ++mi) {
      f32x4 ac = (mi == 0) ? acc0 : acc1;
      int mt = mg * 2 + mi;
      if (n < 256) {
        int s2 = n >> 5, gg = (n >> 3) & 3, e = n & 7;
        size_t base = ((size_t)((b * 128 + mt) * 8 + s2) * 64 + gg * 16) * 8 + e;
#pragma unroll
        for (int rr = 0; rr < 4; ++rr)
          kps[base + (size_t)(g * 4 + rr) * 8] = f16bits(ac[rr] + bb);
      } else {
        int c = n - 256, h = c >> 5, dd = c & 31;
        ushortv4 p;
#pragma unroll
        for (int rr = 0; rr < 4; ++rr) p[rr] = f16bits(ac[rr] + bb);
        *(ushortv4*)(vt + ((size_t)(b * H_ + h) * HD_ + dd) * KL + mt * 16 + g * 4) = p;
      }
    }
  }
}

// ---------- cpb: z-MLP + W2 MFMA; 4-q batch (LDS reads amortized 2x vs R15)
// block = (b, 4 q-rows, 128 k), 256 threads / 4 waves; grid = 2*64*16 = 2048
__global__ __launch_bounds__(256, 4) void cpb_k(
    const float* __restrict__ rd, const float* __restrict__ W1,
    const float* __restrict__ b1, const float* __restrict__ W2,
    unsigned short* __restrict__ cpb4) {
  int gid = blockIdx.x;
  int kcg = gid & 15, qg = (gid >> 4) & 63, b = gid >> 10;
  int t = threadIdx.x;
  __shared__ unsigned int w1xs[128], w1ys[128], b1ps[128];
  __shared__ unsigned short w2h[H_][264];
  if (t < 128) {
    float4 wr = *(const float4*)(W1 + 4 * t);
    w1xs[t] = pkrtz(wr.x, wr.z);
    w1ys[t] = pkrtz(wr.y, wr.w);
    float2 bb = *(const float2*)(b1 + 2 * t);
    b1ps[t] = pkrtz(bb.x, bb.y);
  }
#pragma unroll
  for (int i = 0; i < 2; ++i) {
    int idx = t + i * 256;
    int h = idx >> 6, c0 = (idx & 63) * 4;
    float4 wv = *(const float4*)(W2 + h * CH_ + c0);
    w2h[h][c0 + 0] = f16bits(wv.x);
    w2h[h][c0 + 1] = f16bits(wv.y);
    w2h[h][c0 + 2] = f16bits(wv.z);
    w2h[h][c0 + 3] = f16bits(wv.w);
  }
  __syncthreads();

  int l = t & 63, w = t >> 6;
  int hp = l & 15, g = l >> 4, hq = hp & 7;
  int k0 = kcg * 128 + w * 32;
  int kt0 = k0 >> 4;

  unsigned int x2[4][2], y2[4][2];
#pragma unroll
  for (int q = 0; q < 4; ++q) {
    const float* rdb = rd + ((size_t)(b * Q_ + qg * 4 + q) * KL) * 2;
#pragma unroll
    for (int r = 0; r < 2; ++r) {
      float2 p = *(const float2*)(rdb + (k0 + r * 16 + hp) * 2);
      x2[q][r] = pkrtz(p.x, p.x);
      y2[q][r] = pkrtz(p.y, p.y);
    }
  }

  f32x4 acc[4][2];
#pragma unroll
  for (int q = 0; q < 4; ++q)
#pragma unroll
    for (int r = 0; r < 2; ++r) acc[q][r] = (f32x4){0.f, 0.f, 0.f, 0.f};

#pragma unroll
  for (int s = 0; s < 8; ++s) {
    int pidx = g * 4 + 16 * s;
    uintv4 wx = *(const uintv4*)&w1xs[pidx];
    uintv4 wy = *(const uintv4*)&w1ys[pidx];
    uintv4 bp = *(const uintv4*)&b1ps[pidx];
    f16x8 w2f = *(const f16x8*)&w2h[hq][g * 8 + 32 * s];
#pragma unroll
    for (int q = 0; q < 4; ++q)
#pragma unroll
      for (int r = 0; r < 2; ++r) {
        UH8 az;
#pragma unroll
        for (int m = 0; m < 4; ++m)
          az.u[m] = pk_max0(pk_fma(x2[q][r], wx[m], pk_fma(y2[q][r], wy[m], bp[m])));
        acc[q][r] = __builtin_amdgcn_mfma_f32_16x16x32_f16(az.h, w2f, acc[q][r], 0, 0, 0);
      }
  }

  if (hp < 8) {
#pragma unroll
    for (int q = 0; q < 4; ++q) {
      int qrow = qg * 4 + q;
      int qt = qrow >> 4, qc = qrow & 15;
#pragma unroll
      for (int r = 0; r < 2; ++r) {
        size_t T = ((size_t)(b * 8 + hp) * 128 + kt0 + r) * 16 + qt;
        uint2 pk;
        pk.x = pkrtz(acc[q][r][0], acc[q][r][1]);
        pk.y = pkrtz(acc[q][r][2], acc[q][r][3]);
        *(uint2*)(cpb4 + T * 256 + (g * 16 + qc) * 4) = pk;
      }
    }
  }
}

// ---------- attn: dense QK (+cpb as C) + exact softmax + PV
// block = ((b*8+h)*16 + qt), 1024 threads / 16 waves; wave -> 128 k
__global__ __launch_bounds__(1024) void attn(
    const unsigned short* __restrict__ qpf, const unsigned short* __restrict__ kps,
    const unsigned short* __restrict__ cpb4, const unsigned short* __restrict__ vt,
    unsigned short* __restrict__ ctxb) {
  int gid = blockIdx.x;
  int qt = gid & 15, bh = gid >> 4;
  int b = bh >> 3, h = bh & 7;
  int t = threadIdx.x, w = t >> 6, l = t & 63;
  int qq = l & 15, g = l >> 4;
  __shared__ unsigned short Plds[16][16][128];  // 64 KB, XOR-swizzled rows
  __shared__ float wredM[16][16];
  __shared__ float wredS[16][16];
  __shared__ float pacc[16][16][33];

  // q B-fragment (scale already folded)
  UH8 qB;
  {
    const unsigned int* qpu = (const unsigned int*)qpf;
    uintv4 qv = *(const uintv4*)(qpu + ((size_t)((b * 16 + qt) * 8 + h)) * 256 + l * 4);
#pragma unroll
    for (int m = 0; m < 4; ++m) qB.u[m] = qv[m];
  }

  // QK: 8 tiles per wave, C-init = cpb
  const f16x8* ka = (const f16x8*)kps + ((size_t)(b * 128) * 8) * 64 + l;
  const unsigned short* cb = cpb4 + ((size_t)bh * 128 * 16 + qt) * 256 + l * 4;
  f32x4 S[8];
#pragma unroll
  for (int i = 0; i < 8; ++i) {
    int kt = w * 8 + i;
    uint2 c2 = *(const uint2*)(cb + (size_t)kt * 4096);
    f32x4 C;
    C[0] = h2f((unsigned short)(c2.x & 0xffff));
    C[1] = h2f((unsigned short)(c2.x >> 16));
    C[2] = h2f((unsigned short)(c2.y & 0xffff));
    C[3] = h2f((unsigned short)(c2.y >> 16));
    f16x8 af = ka[((size_t)kt * 8 + h) * 64];
    S[i] = __builtin_amdgcn_mfma_f32_16x16x32_f16(af, qB.h, C, 0, 0, 0);
  }

  // block max per q-col
  float m = -3.0e38f;
#pragma unroll
  for (int i = 0; i < 8; ++i)
#pragma unroll
    for (int rr = 0; rr < 4; ++rr) m = fmaxf(m, S[i][rr]);
  m = fmaxf(m, __shfl_xor(m, 16));
  m = fmaxf(m, __shfl_xor(m, 32));
  if (l < 16) wredM[w][l] = m;
  __syncthreads();
  float M = wredM[0][qq];
#pragma unroll
  for (int wv = 1; wv < 16; ++wv) M = fmaxf(M, wredM[wv][qq]);

  // exp + P_lds (per-wave region, XOR swizzle) + sum
  float ss = 0.f;
  char* prow = (char*)&Plds[w][qq][0];
  int xr = (qq & 7) << 4;
#pragma unroll
  for (int i = 0; i < 8; ++i) {
    float p0 = __expf(S[i][0] - M);
    float p1 = __expf(S[i][1] - M);
    float p2 = __expf(S[i][2] - M);
    float p3 = __expf(S[i][3] - M);
    ss += (p0 + p1) + (p2 + p3);
    uint2 pk;
    pk.x = pkrtz(p0, p1);
    pk.y = pkrtz(p2, p3);
    *(uint2*)(prow + ((i * 32 + g * 8) ^ xr)) = pk;
  }
  ss += __shfl_xor(ss, 16);
  ss += __shfl_xor(ss, 32);
  if (l < 16) wredS[w][l] = ss;

  // PV over own 128-k range
  const unsigned short* vb0 = vt + ((size_t)bh * HD_ + qq) * KL + w * 128 + g * 8;
  const unsigned short* vb1 = vb0 + (size_t)16 * KL;
  f32x4 a0 = {0.f, 0.f, 0.f, 0.f}, a1 = {0.f, 0.f, 0.f, 0.f};
#pragma unroll
  for (int cw = 0; cw < 4; ++cw) {
    f16x8 pa = *(const f16x8*)(prow + ((cw * 64 + g * 16) ^ xr));
    f16x8 v0 = *(const f16x8*)(vb0 + cw * 32);
    f16x8 v1 = *(const f16x8*)(vb1 + cw * 32);
    a0 = __builtin_amdgcn_mfma_f32_16x16x32_f16(pa, v0, a0, 0, 0, 0);
    a1 = __builtin_amdgcn_mfma_f32_16x16x32_f16(pa, v1, a1, 0, 0, 0);
  }
#pragma unroll
  for (int rr = 0; rr < 4; ++rr) {
    pacc[w][g * 4 + rr][qq] = a0[rr];
    pacc[w][g * 4 + rr][qq + 16] = a1[rr];
  }
  __syncthreads();

  if (t < 512) {
    int qo = t >> 5, dd = t & 31;
    float sum = 0.f, st = 0.f;
#pragma unroll
    for (int wv = 0; wv < 16; ++wv) {
      sum += pacc[wv][qo][dd];
      st += wredS[wv][qo];
    }
    ctxb[((size_t)b * Q_ + qt * 16 + qo) * D_ + h * HD_ + dd] = f16bits(sum / st);
  }
}

// ---------- out projection: out = ctxb(f16) @ Wo^T + bo (fp32 out)
__global__ __launch_bounds__(256) void gemm_o(const unsigned short* __restrict__ A,
                                              const unsigned short* __restrict__ WoS,
                                              const float* __restrict__ bias,
                                              float* __restrict__ out) {
  int nt = blockIdx.x & 3, mt = blockIdx.x >> 2;
  int t = threadIdx.x, w = t >> 6, l = t & 63;
  int m0 = mt * 16;
  int r = l & 15, g = l >> 4;
  const unsigned short* arow = A + (size_t)(m0 + r) * D_;
  int tB = nt * 4 + w;
  f16x8 af[8], bf[8];
#pragma unroll
  for (int s = 0; s < 8; ++s) {
    af[s] = *(const f16x8*)(arow + s * 32 + g * 8);
    bf[s] = ((const f16x8*)WoS)[(tB * 8 + s) * 64 + l];
  }
  f32x4 acc = {0.f, 0.f, 0.f, 0.f};
#pragma unroll
  for (int s = 0; s < 8; ++s)
    acc = __builtin_amdgcn_mfma_f32_16x16x32_f16(af[s], bf[s], acc, 0, 0, 0);
  int n = nt * 64 + w * 16 + r;
  float bb = bias[n];
#pragma unroll
  for (int rr = 0; rr < 4; ++rr)
    out[(size_t)(m0 + g * 4 + rr) * D_ + n] = acc[rr] + bb;
}

extern "C" void kernel_launch(void* const* d_in, const int* in_sizes, int n_in,
                              void* d_out, int out_size, void* d_ws, size_t ws_size,
                              hipStream_t stream) {
  const float* ent  = (const float*)d_in[0];
  const float* img  = (const float*)d_in[1];
  const float* rd   = (const float*)d_in[2];
  const float* Wq   = (const float*)d_in[3];
  const float* bq   = (const float*)d_in[4];
  const float* Wkv  = (const float*)d_in[5];
  const float* bkv  = (const float*)d_in[6];
  const float* W1   = (const float*)d_in[7];
  const float* b1   = (const float*)d_in[8];
  const float* W2   = (const float*)d_in[9];
  const float* b2   = (const float*)d_in[10];
  const float* Wo   = (const float*)d_in[11];
  const float* bo   = (const float*)d_in[12];
  float* out = (float*)d_out;
  (void)b2;  // cancels in softmax (constant per row)

  char* ws = (char*)d_ws;
  unsigned short* kps   = (unsigned short*)(ws + 0);         // 2,097,152 f16 swizzled K
  unsigned short* vt    = (unsigned short*)(ws + 2097152);   // 2,097,152 f16 [b][h][dd][k]
  unsigned short* cpb4  = (unsigned short*)(ws + 4194304);   // 16,777,216 f16 cpb fragments
  unsigned short* ctxb  = (unsigned short*)(ws + 20971520);  //   262,144 f16 [b][q][c]
  unsigned short* qpf   = (unsigned short*)(ws + 21233664);  //   262,144 f16 q fragments
  unsigned short* entS  = (unsigned short*)(ws + 21495808);  //   262,144 f16 frag
  unsigned short* imgS  = (unsigned short*)(ws + 21757952);  // 2,097,152 f16 frag
  unsigned short* WqS   = (unsigned short*)(ws + 23855104);  //   131,072 f16 frag
  unsigned short* WkvS  = (unsigned short*)(ws + 23986176);  //   262,144 f16 frag
  unsigned short* WoS   = (unsigned short*)(ws + 24248320);  //   131,072 f16 frag

  prep<<<dim3(352), dim3(512), 0, stream>>>(ent, img, Wq, Wkv, Wo,
                                            entS, imgS, WqS, WkvS, WoS);
  gemm2<<<dim3(64 + 1024), dim3(256), 0, stream>>>(entS, WqS, bq, qpf,
                                                   imgS, WkvS, bkv, kps, vt);
  cpb_k<<<dim3(2048), dim3(256), 0, stream>>>(rd, W1, b1, W2, cpb4);
  attn<<<dim3(B_ * H_ * 16), dim3(1024), 0, stream>>>(qpf, kps, cpb4, vt, ctxb);
  gemm_o<<<dim3(128), dim3(256), 0, stream>>>(ctxb, WoS, bo, out);
}

// Round 17
// 51.252 us; speedup vs baseline: 1.1966x; 1.0654x over previous
//
#include <hip/hip_runtime.h>
#include <hip/hip_bf16.h>
#include <cstdint>
#include <cstddef>

#define B_  2
#define Q_  256
#define KL  2048
#define D_  256
#define H_  8
#define HD_ 32
#define CH_ 256

typedef _Float16 f16;
typedef __fp16 fp16x2 __attribute__((ext_vector_type(2)));
typedef _Float16 f16x8 __attribute__((ext_vector_type(8)));
typedef unsigned short ushortv4 __attribute__((ext_vector_type(4)));
typedef unsigned int uintv4 __attribute__((ext_vector_type(4)));
typedef float f32x4 __attribute__((ext_vector_type(4)));

union UH  { fp16x2 h; unsigned int u; };
union UH8 { f16x8 h; unsigned int u[4]; };

__device__ __forceinline__ unsigned int pkrtz(float a, float b) {
  UH r; r.h = __builtin_amdgcn_cvt_pkrtz(a, b); return r.u;
}
__device__ __forceinline__ unsigned short f16bits(float a) {
  return (unsigned short)(pkrtz(a, 0.f) & 0xffffu);
}
__device__ __forceinline__ float h2f(unsigned short u) {
  __fp16 h = *(__fp16*)&u;
  return (float)h;
}
__device__ __forceinline__ unsigned int pk_fma(unsigned int a, unsigned int b,
                                               unsigned int c) {
  unsigned int d;
  asm("v_pk_fma_f16 %0, %1, %2, %3" : "=v"(d) : "v"(a), "v"(b), "v"(c));
  return d;
}
__device__ __forceinline__ unsigned int pk_max0(unsigned int a) {
  unsigned int d;
  asm("v_pk_max_f16 %0, %1, %2" : "=v"(d) : "v"(a), "v"(0u));
  return d;
}

// ---------- prep: fp32 row-major -> f16 MFMA-fragment layout
__global__ __launch_bounds__(512) void prep(
    const float* __restrict__ ent, const float* __restrict__ img,
    const float* __restrict__ Wq, const float* __restrict__ Wkv,
    const float* __restrict__ Wo,
    unsigned short* __restrict__ entS, unsigned short* __restrict__ imgS,
    unsigned short* __restrict__ WqS, unsigned short* __restrict__ WkvS,
    unsigned short* __restrict__ WoS) {
  int bid = blockIdx.x, t = threadIdx.x;
  const float* src;
  unsigned short* dst;
  if (bid < 32)       { src = ent + (size_t)bid * 16 * D_;          dst = entS + (size_t)bid * 4096; }
  else if (bid < 288) { int k = bid - 32;  src = img + (size_t)k * 16 * D_; dst = imgS + (size_t)k * 4096; }
  else if (bid < 304) { int k = bid - 288; src = Wq  + (size_t)k * 16 * D_; dst = WqS  + (size_t)k * 4096; }
  else if (bid < 336) { int k = bid - 304; src = Wkv + (size_t)k * 16 * D_; dst = WkvS + (size_t)k * 4096; }
  else                { int k = bid - 336; src = Wo  + (size_t)k * 16 * D_; dst = WoS  + (size_t)k * 4096; }
  __shared__ float rows[16][257];
  {
    int rr = t >> 5, c0 = (t & 31) * 8;
    float4 a = *(const float4*)(src + rr * D_ + c0);
    float4 b = *(const float4*)(src + rr * D_ + c0 + 4);
    rows[rr][c0 + 0] = a.x; rows[rr][c0 + 1] = a.y;
    rows[rr][c0 + 2] = a.z; rows[rr][c0 + 3] = a.w;
    rows[rr][c0 + 4] = b.x; rows[rr][c0 + 5] = b.y;
    rows[rr][c0 + 6] = b.z; rows[rr][c0 + 7] = b.w;
  }
  __syncthreads();
  int s = t >> 6, l = t & 63, r = l & 15, g = l >> 4;
  const float* rp = &rows[r][s * 32 + g * 8];
  UH8 u;
#pragma unroll
  for (int m = 0; m < 4; ++m) u.u[m] = pkrtz(rp[2 * m], rp[2 * m + 1]);
  ((f16x8*)dst)[s * 64 + l] = u.h;
}

// ---------- fused mid-kernel: blocks [0,2048) = cpb; [2048,3136) = q/kv proj
// cpb: z-MLP + W2 MFMA -> cpb4 fragments. proj: from fragment-swizzled inputs.
__global__ __launch_bounds__(256) void mid(
    const float* __restrict__ rd, const float* __restrict__ W1,
    const float* __restrict__ b1, const float* __restrict__ W2,
    unsigned short* __restrict__ cpb4,
    const unsigned short* __restrict__ entS, const unsigned short* __restrict__ WqS,
    const float* __restrict__ bq, unsigned short* __restrict__ qpf,
    const unsigned short* __restrict__ imgS, const unsigned short* __restrict__ WkvS,
    const float* __restrict__ bkv, unsigned short* __restrict__ kps,
    unsigned short* __restrict__ vt) {
  int bid0 = blockIdx.x;
  int t = threadIdx.x, w = t >> 6, l = t & 63;
  const float scale = 0.17677669529663687f;  // 1/sqrt(32)
  if (bid0 < 2048) {
    // ---- cpb branch ----
    int gid = bid0;
    int kcg = gid & 15, qg = (gid >> 4) & 63, b = gid >> 10;
    __shared__ unsigned int w1xs[128], w1ys[128], b1ps[128];
    __shared__ unsigned short w2h[H_][264];
    if (t < 128) {
      float4 wr = *(const float4*)(W1 + 4 * t);
      w1xs[t] = pkrtz(wr.x, wr.z);
      w1ys[t] = pkrtz(wr.y, wr.w);
      float2 bb = *(const float2*)(b1 + 2 * t);
      b1ps[t] = pkrtz(bb.x, bb.y);
    }
#pragma unroll
    for (int i = 0; i < 2; ++i) {
      int idx = t + i * 256;
      int h = idx >> 6, c0 = (idx & 63) * 4;
      float4 wv = *(const float4*)(W2 + h * CH_ + c0);
      w2h[h][c0 + 0] = f16bits(wv.x);
      w2h[h][c0 + 1] = f16bits(wv.y);
      w2h[h][c0 + 2] = f16bits(wv.z);
      w2h[h][c0 + 3] = f16bits(wv.w);
    }
    __syncthreads();

    int hp = l & 15, g = l >> 4;
    int k0 = kcg * 128 + w * 32;
    int kt0 = k0 >> 4;

    unsigned int x2[4][2], y2[4][2];
#pragma unroll
    for (int q = 0; q < 4; ++q) {
      const float* rdb = rd + ((size_t)(b * Q_ + qg * 4 + q) * KL) * 2;
#pragma unroll
      for (int r = 0; r < 2; ++r) {
        float2 p = *(const float2*)(rdb + (k0 + r * 16 + hp) * 2);
        x2[q][r] = pkrtz(p.x, p.x);
        y2[q][r] = pkrtz(p.y, p.y);
      }
    }

    f32x4 acc[4][2];
#pragma unroll
    for (int q = 0; q < 4; ++q)
#pragma unroll
      for (int r = 0; r < 2; ++r) acc[q][r] = (f32x4){0.f, 0.f, 0.f, 0.f};

    int hq = hp & 7;
#pragma unroll
    for (int s = 0; s < 8; ++s) {
      int pidx = g * 4 + 16 * s;
      uintv4 wx = *(const uintv4*)&w1xs[pidx];
      uintv4 wy = *(const uintv4*)&w1ys[pidx];
      uintv4 bp = *(const uintv4*)&b1ps[pidx];
      f16x8 w2f = *(const f16x8*)&w2h[hq][g * 8 + 32 * s];
#pragma unroll
      for (int q = 0; q < 4; ++q)
#pragma unroll
        for (int r = 0; r < 2; ++r) {
          UH8 az;
#pragma unroll
          for (int m = 0; m < 4; ++m)
            az.u[m] = pk_max0(pk_fma(x2[q][r], wx[m], pk_fma(y2[q][r], wy[m], bp[m])));
          acc[q][r] = __builtin_amdgcn_mfma_f32_16x16x32_f16(az.h, w2f, acc[q][r], 0, 0, 0);
        }
    }

    if (hp < 8) {
#pragma unroll
      for (int q = 0; q < 4; ++q) {
        int qrow = qg * 4 + q;
        int qt = qrow >> 4, qc = qrow & 15;
#pragma unroll
        for (int r = 0; r < 2; ++r) {
          size_t T = ((size_t)(b * 8 + hp) * 128 + kt0 + r) * 16 + qt;
          uint2 pk;
          pk.x = pkrtz(acc[q][r][0], acc[q][r][1]);
          pk.y = pkrtz(acc[q][r][2], acc[q][r][3]);
          *(uint2*)(cpb4 + T * 256 + (g * 16 + qc) * 4) = pk;
        }
      }
    }
  } else {
    // ---- projection branch ----
    int bid = bid0 - 2048;
    int r = l & 15, g = l >> 4;
    if (bid < 64) {
      int nt = bid & 3, mg = bid >> 2;
      const f16x8* A = (const f16x8*)entS;
      const f16x8* Bf = (const f16x8*)WqS;
      int tA0 = mg * 2, tB = nt * 4 + w;
      f16x8 a0[8], a1[8], bf[8];
#pragma unroll
      for (int s = 0; s < 8; ++s) {
        a0[s] = A[(tA0 * 8 + s) * 64 + l];
        a1[s] = A[((tA0 + 1) * 8 + s) * 64 + l];
        bf[s] = Bf[(tB * 8 + s) * 64 + l];
      }
      f32x4 acc0 = {0.f, 0.f, 0.f, 0.f}, acc1 = {0.f, 0.f, 0.f, 0.f};
#pragma unroll
      for (int s = 0; s < 8; ++s) {
        acc0 = __builtin_amdgcn_mfma_f32_16x16x32_f16(a0[s], bf[s], acc0, 0, 0, 0);
        acc1 = __builtin_amdgcn_mfma_f32_16x16x32_f16(a1[s], bf[s], acc1, 0, 0, 0);
      }
      int n = nt * 64 + w * 16 + r;
      float bb = bq[n];
      int h = n >> 5, gq = (n >> 3) & 3, e = n & 7;
      int m0 = mg * 32;
#pragma unroll
      for (int half = 0; half < 2; ++half) {
        f32x4 ac = half ? acc1 : acc0;
#pragma unroll
        for (int rr = 0; rr < 4; ++rr) {
          int row = m0 + half * 16 + g * 4 + rr;
          int qt_g = row >> 4, rq = row & 15;
          qpf[((size_t)(qt_g * 8 + h)) * 512 + (gq * 16 + rq) * 8 + e] =
              f16bits((ac[rr] + bb) * scale);
        }
      }
    } else {
      int bid2 = bid - 64;
      int nt = bid2 & 7, mg = (bid2 >> 3) & 63, b = bid2 >> 9;
      const f16x8* A = (const f16x8*)imgS;
      const f16x8* Bf = (const f16x8*)WkvS;
      int tA0 = b * 128 + mg * 2, tB = nt * 4 + w;
      f16x8 a0[8], a1[8], bf[8];
#pragma unroll
      for (int s = 0; s < 8; ++s) {
        a0[s] = A[(tA0 * 8 + s) * 64 + l];
        a1[s] = A[((tA0 + 1) * 8 + s) * 64 + l];
        bf[s] = Bf[(tB * 8 + s) * 64 + l];
      }
      f32x4 acc0 = {0.f, 0.f, 0.f, 0.f}, acc1 = {0.f, 0.f, 0.f, 0.f};
#pragma unroll
      for (int s = 0; s < 8; ++s) {
        acc0 = __builtin_amdgcn_mfma_f32_16x16x32_f16(a0[s], bf[s], acc0, 0, 0, 0);
        acc1 = __builtin_amdgcn_mfma_f32_16x16x32_f16(a1[s], bf[s], acc1, 0, 0, 0);
      }
      int n = nt * 64 + w * 16 + r;
      float bb = bkv[n];
#pragma unroll
      for (int mi = 0; mi < 2; ++mi) {
        f32x4 ac = (mi == 0) ? acc0 : acc1;
        int mt = mg * 2 + mi;
        if (n < 256) {
          int s2 = n >> 5, gg = (n >> 3) & 3, e = n & 7;
          size_t base = ((size_t)((b * 128 + mt) * 8 + s2) * 64 + gg * 16) * 8 + e;
#pragma unroll
          for (int rr = 0; rr < 4; ++rr)
            kps[base + (size_t)(g * 4 + rr) * 8] = f16bits(ac[rr] + bb);
        } else {
          int c = n - 256, h = c >> 5, dd = c & 31;
          ushortv4 p;
#pragma unroll
          for (int rr = 0; rr < 4; ++rr) p[rr] = f16bits(ac[rr] + bb);
          *(ushortv4*)(vt + ((size_t)(b * H_ + h) * HD_ + dd) * KL + mt * 16 + g * 4) = p;
        }
      }
    }
  }
}

// ---------- attn: dense QK (+cpb as C) + exact softmax + PV
// block = ((b*8+h)*16 + qt), 1024 threads / 16 waves; wave -> 128 k
__global__ __launch_bounds__(1024) void attn(
    const unsigned short* __restrict__ qpf, const unsigned short* __restrict__ kps,
    const unsigned short* __restrict__ cpb4, const unsigned short* __restrict__ vt,
    unsigned short* __restrict__ ctxb) {
  int gid = blockIdx.x;
  int qt = gid & 15, bh = gid >> 4;
  int b = bh >> 3, h = bh & 7;
  int t = threadIdx.x, w = t >> 6, l = t & 63;
  int qq = l & 15, g = l >> 4;
  __shared__ unsigned short Plds[16][16][128];  // 64 KB, XOR-swizzled rows
  __shared__ float wredM[16][16];
  __shared__ float wredS[16][16];
  __shared__ float pacc[16][16][33];

  UH8 qB;
  {
    const unsigned int* qpu = (const unsigned int*)qpf;
    uintv4 qv = *(const uintv4*)(qpu + ((size_t)((b * 16 + qt) * 8 + h)) * 256 + l * 4);
#pragma unroll
    for (int m = 0; m < 4; ++m) qB.u[m] = qv[m];
  }

  const f16x8* ka = (const f16x8*)kps + ((size_t)(b * 128) * 8) * 64 + l;
  const unsigned short* cb = cpb4 + ((size_t)bh * 128 * 16 + qt) * 256 + l * 4;
  f32x4 S[8];
#pragma unroll
  for (int i = 0; i < 8; ++i) {
    int kt = w * 8 + i;
    uint2 c2 = *(const uint2*)(cb + (size_t)kt * 4096);
    f32x4 C;
    C[0] = h2f((unsigned short)(c2.x & 0xffff));
    C[1] = h2f((unsigned short)(c2.x >> 16));
    C[2] = h2f((unsigned short)(c2.y & 0xffff));
    C[3] = h2f((unsigned short)(c2.y >> 16));
    f16x8 af = ka[((size_t)kt * 8 + h) * 64];
    S[i] = __builtin_amdgcn_mfma_f32_16x16x32_f16(af, qB.h, C, 0, 0, 0);
  }

  float m = -3.0e38f;
#pragma unroll
  for (int i = 0; i < 8; ++i)
#pragma unroll
    for (int rr = 0; rr < 4; ++rr) m = fmaxf(m, S[i][rr]);
  m = fmaxf(m, __shfl_xor(m, 16));
  m = fmaxf(m, __shfl_xor(m, 32));
  if (l < 16) wredM[w][l] = m;
  __syncthreads();
  float M = wredM[0][qq];
#pragma unroll
  for (int wv = 1; wv < 16; ++wv) M = fmaxf(M, wredM[wv][qq]);

  float ss = 0.f;
  char* prow = (char*)&Plds[w][qq][0];
  int xr = (qq & 7) << 4;
#pragma unroll
  for (int i = 0; i < 8; ++i) {
    float p0 = __expf(S[i][0] - M);
    float p1 = __expf(S[i][1] - M);
    float p2 = __expf(S[i][2] - M);
    float p3 = __expf(S[i][3] - M);
    ss += (p0 + p1) + (p2 + p3);
    uint2 pk;
    pk.x = pkrtz(p0, p1);
    pk.y = pkrtz(p2, p3);
    *(uint2*)(prow + ((i * 32 + g * 8) ^ xr)) = pk;
  }
  ss += __shfl_xor(ss, 16);
  ss += __shfl_xor(ss, 32);
  if (l < 16) wredS[w][l] = ss;

  const unsigned short* vb0 = vt + ((size_t)bh * HD_ + qq) * KL + w * 128 + g * 8;
  const unsigned short* vb1 = vb0 + (size_t)16 * KL;
  f32x4 a0 = {0.f, 0.f, 0.f, 0.f}, a1 = {0.f, 0.f, 0.f, 0.f};
#pragma unroll
  for (int cw = 0; cw < 4; ++cw) {
    f16x8 pa = *(const f16x8*)(prow + ((cw * 64 + g * 16) ^ xr));
    f16x8 v0 = *(const f16x8*)(vb0 + cw * 32);
    f16x8 v1 = *(const f16x8*)(vb1 + cw * 32);
    a0 = __builtin_amdgcn_mfma_f32_16x16x32_f16(pa, v0, a0, 0, 0, 0);
    a1 = __builtin_amdgcn_mfma_f32_16x16x32_f16(pa, v1, a1, 0, 0, 0);
  }
#pragma unroll
  for (int rr = 0; rr < 4; ++rr) {
    pacc[w][g * 4 + rr][qq] = a0[rr];
    pacc[w][g * 4 + rr][qq + 16] = a1[rr];
  }
  __syncthreads();

  if (t < 512) {
    int qo = t >> 5, dd = t & 31;
    float sum = 0.f, st = 0.f;
#pragma unroll
    for (int wv = 0; wv < 16; ++wv) {
      sum += pacc[wv][qo][dd];
      st += wredS[wv][qo];
    }
    ctxb[((size_t)b * Q_ + qt * 16 + qo) * D_ + h * HD_ + dd] = f16bits(sum / st);
  }
}

// ---------- out projection: out = ctxb(f16) @ Wo^T + bo (fp32 out)
__global__ __launch_bounds__(256) void gemm_o(const unsigned short* __restrict__ A,
                                              const unsigned short* __restrict__ WoS,
                                              const float* __restrict__ bias,
                                              float* __restrict__ out) {
  int nt = blockIdx.x & 3, mt = blockIdx.x >> 2;
  int t = threadIdx.x, w = t >> 6, l = t & 63;
  int m0 = mt * 16;
  int r = l & 15, g = l >> 4;
  const unsigned short* arow = A + (size_t)(m0 + r) * D_;
  int tB = nt * 4 + w;
  f16x8 af[8], bf[8];
#pragma unroll
  for (int s = 0; s < 8; ++s) {
    af[s] = *(const f16x8*)(arow + s * 32 + g * 8);
    bf[s] = ((const f16x8*)WoS)[(tB * 8 + s) * 64 + l];
  }
  f32x4 acc = {0.f, 0.f, 0.f, 0.f};
#pragma unroll
  for (int s = 0; s < 8; ++s)
    acc = __builtin_amdgcn_mfma_f32_16x16x32_f16(af[s], bf[s], acc, 0, 0, 0);
  int n = nt * 64 + w * 16 + r;
  float bb = bias[n];
#pragma unroll
  for (int rr = 0; rr < 4; ++rr)
    out[(size_t)(m0 + g * 4 + rr) * D_ + n] = acc[rr] + bb;
}

extern "C" void kernel_launch(void* const* d_in, const int* in_sizes, int n_in,
                              void* d_out, int out_size, void* d_ws, size_t ws_size,
                              hipStream_t stream) {
  const float* ent  = (const float*)d_in[0];
  const float* img  = (const float*)d_in[1];
  const float* rd   = (const float*)d_in[2];
  const float* Wq   = (const float*)d_in[3];
  const float* bq   = (const float*)d_in[4];
  const float* Wkv  = (const float*)d_in[5];
  const float* bkv  = (const float*)d_in[6];
  const float* W1   = (const float*)d_in[7];
  const float* b1   = (const float*)d_in[8];
  const float* W2   = (const float*)d_in[9];
  const float* b2   = (const float*)d_in[10];
  const float* Wo   = (const float*)d_in[11];
  const float* bo   = (const float*)d_in[12];
  float* out = (float*)d_out;
  (void)b2;  // cancels in softmax (constant per row)

  char* ws = (char*)d_ws;
  unsigned short* kps   = (unsigned short*)(ws + 0);         // 2,097,152 f16 swizzled K
  unsigned short* vt    = (unsigned short*)(ws + 2097152);   // 2,097,152 f16 [b][h][dd][k]
  unsigned short* cpb4  = (unsigned short*)(ws + 4194304);   // 16,777,216 f16 cpb fragments
  unsigned short* ctxb  = (unsigned short*)(ws + 20971520);  //   262,144 f16 [b][q][c]
  unsigned short* qpf   = (unsigned short*)(ws + 21233664);  //   262,144 f16 q fragments
  unsigned short* entS  = (unsigned short*)(ws + 21495808);  //   262,144 f16 frag
  unsigned short* imgS  = (unsigned short*)(ws + 21757952);  // 2,097,152 f16 frag
  unsigned short* WqS   = (unsigned short*)(ws + 23855104);  //   131,072 f16 frag
  unsigned short* WkvS  = (unsigned short*)(ws + 23986176);  //   262,144 f16 frag
  unsigned short* WoS   = (unsigned short*)(ws + 24248320);  //   131,072 f16 frag

  prep<<<dim3(352), dim3(512), 0, stream>>>(ent, img, Wq, Wkv, Wo,
                                            entS, imgS, WqS, WkvS, WoS);
  mid<<<dim3(2048 + 64 + 1024), dim3(256), 0, stream>>>(
      rd, W1, b1, W2, cpb4, entS, WqS, bq, qpf, imgS, WkvS, bkv, kps, vt);
  attn<<<dim3(B_ * H_ * 16), dim3(1024), 0, stream>>>(qpf, kps, cpb4, vt, ctxb);
  gemm_o<<<dim3(128), dim3(256), 0, stream>>>(ctxb, WoS, bo, out);
}